// Round 1
// baseline (171.297 us; speedup 1.0000x reference)
//
#include <hip/hip_runtime.h>
#include <math.h>

// One thread per sample. Fully unrolled: 10x10 input in registers, all wrap
// indices compile-time. fp32 throughout (sign(z) fidelity requires it; no
// fp32 MFMA on CDNA4 anyway). Sign product via XOR of sign bits; logs paired
// (log2(|z0*z1|)) to halve transcendental count, single *ln2 at the end.
__global__ __launch_bounds__(256) void CNN2D_37495064494620_kernel(
    const float* __restrict__ v,
    const float* __restrict__ cw,   // [4,1,3,3]
    const float* __restrict__ cb,   // [4]
    const float* __restrict__ dw,   // [4,1,2,2]
    const float* __restrict__ db,   // [1]
    float* __restrict__ out,        // [2*B]: [0,B)=sign_prod, [B,2B)=log_sum
    int B)
{
    const int b = blockIdx.x * 256 + threadIdx.x;
    if (b >= B) return;

    // Uniform weight loads -> scalar regs (address independent of lane).
    float W[4][9];
    #pragma unroll
    for (int f = 0; f < 4; ++f)
        #pragma unroll
        for (int t = 0; t < 9; ++t)
            W[f][t] = cw[f * 9 + t];
    float Cb[4];
    #pragma unroll
    for (int f = 0; f < 4; ++f) Cb[f] = cb[f];
    float Dw[4][4];
    #pragma unroll
    for (int f = 0; f < 4; ++f)
        #pragma unroll
        for (int t = 0; t < 4; ++t)
            Dw[f][t] = dw[f * 4 + t];
    const float Db = db[0];

    // Load the 10x10 sample into registers (25 x float4; row base 400B -> 16B aligned).
    float X[100];
    const float4* src = (const float4*)(v + (size_t)b * 100);
    #pragma unroll
    for (int t = 0; t < 25; ++t) {
        float4 q = src[t];
        X[4 * t + 0] = q.x;
        X[4 * t + 1] = q.y;
        X[4 * t + 2] = q.z;
        X[4 * t + 3] = q.w;
    }

    unsigned sbits = 0u;   // XOR of z sign bits
    float l2 = 0.0f;       // sum of log2|z|

    #pragma unroll
    for (int i = 0; i < 5; ++i) {
        #pragma unroll
        for (int j = 0; j < 5; ++j) {
            // Pooled cell (i,j): max over conv outputs at rows 2i..2i+1, cols 2j..2j+1.
            float p0, p1, p2, p3;
            #pragma unroll
            for (int dr = 0; dr < 2; ++dr) {
                #pragma unroll
                for (int dc = 0; dc < 2; ++dc) {
                    const int r = 2 * i + dr, c = 2 * j + dc;
                    float a0 = Cb[0], a1 = Cb[1], a2 = Cb[2], a3 = Cb[3];
                    #pragma unroll
                    for (int kr = 0; kr < 3; ++kr) {
                        const int rr = (r + kr + 9) % 10;   // wrap, compile-time
                        #pragma unroll
                        for (int kc = 0; kc < 3; ++kc) {
                            const int cc = (c + kc + 9) % 10;
                            const float xv = X[rr * 10 + cc];
                            const int t = kr * 3 + kc;
                            a0 = fmaf(xv, W[0][t], a0);
                            a1 = fmaf(xv, W[1][t], a1);
                            a2 = fmaf(xv, W[2][t], a2);
                            a3 = fmaf(xv, W[3][t], a3);
                        }
                    }
                    if (dr == 0 && dc == 0) {
                        p0 = a0; p1 = a1; p2 = a2; p3 = a3;
                    } else {
                        p0 = fmaxf(p0, a0); p1 = fmaxf(p1, a1);
                        p2 = fmaxf(p2, a2); p3 = fmaxf(p3, a3);
                    }
                }
            }
            // Deconv: z[2i+k][2j+l] = sum_f p_f * Dw[f][k*2+l] + Db
            float z[4];
            #pragma unroll
            for (int kl = 0; kl < 4; ++kl) {
                float zz = Db;
                zz = fmaf(p0, Dw[0][kl], zz);
                zz = fmaf(p1, Dw[1][kl], zz);
                zz = fmaf(p2, Dw[2][kl], zz);
                zz = fmaf(p3, Dw[3][kl], zz);
                z[kl] = zz;
                sbits ^= __float_as_uint(zz);
            }
            // Pairwise products halve the transcendental count; |z0*z1| in
            // [~1e-18, ~1e4] -> safely inside fp32 normal range.
            l2 += __log2f(fabsf(z[0] * z[1])) + __log2f(fabsf(z[2] * z[3]));
        }
    }

    out[b]     = (sbits & 0x80000000u) ? -1.0f : 1.0f;
    out[B + b] = l2 * 0.69314718055994531f;  // ln2 * sum(log2|z|)
}

extern "C" void kernel_launch(void* const* d_in, const int* in_sizes, int n_in,
                              void* d_out, int out_size, void* d_ws, size_t ws_size,
                              hipStream_t stream) {
    const float* v  = (const float*)d_in[0];
    const float* cw = (const float*)d_in[1];
    const float* cb = (const float*)d_in[2];
    const float* dw = (const float*)d_in[3];
    const float* db = (const float*)d_in[4];
    float* out = (float*)d_out;

    const int B = in_sizes[0] / 100;
    const int grid = (B + 255) / 256;
    CNN2D_37495064494620_kernel<<<grid, 256, 0, stream>>>(v, cw, cb, dw, db, out, B);
}